// Round 2
// baseline (360.569 us; speedup 1.0000x reference)
//
#include <hip/hip_runtime.h>
#include <math.h>

#define PI_F 3.14159265358979323846f

// Problem constants: x (8,1,2048,2048) fp32 -> out (8,16,128,128) fp32
// Patches: 16x16, D_in=256, D=16, 131072 patches total (16384 per batch).

// Workspace float offsets
#define WS_M     0      // M[16][256]
#define WS_V     4096   // v[16]
#define WS_A     4352   // A[16][256]
#define WS_U     8448   // u[16]
#define WS_STATS 8464   // sum[64], sumsq[64]

// ---------------------------------------------------------------------------
// prep1: M[m][n] = (1/64) Re( sum_k e^{-2pi i k n/256} * T[m][k] )
//        T[m][k] = sum_d Wc[d][k] e^{+2pi i d m/16},  Wc = wr + i*wi
//        v[m]    = (1/4)  Re( sum_d (br[d]+i*bi[d]) e^{+2pi i d m/16} )
// ---------------------------------------------------------------------------
__global__ void prep1(const float* __restrict__ wr, const float* __restrict__ wi,
                      const float* __restrict__ br, const float* __restrict__ bi,
                      float* __restrict__ M, float* __restrict__ v) {
    const int m = blockIdx.x;
    const int t = threadIdx.x;
    __shared__ float Tr[256], Ti[256], cosT[256], sinT[256], cd[16], sd[16];

    float ang = (2.0f * PI_F / 256.0f) * (float)t;
    cosT[t] = cosf(ang);
    sinT[t] = sinf(ang);
    if (t < 16) {
        float a = (2.0f * PI_F / 16.0f) * (float)((t * m) & 15);
        cd[t] = cosf(a);
        sd[t] = sinf(a);
    }
    __syncthreads();

    float tr = 0.f, ti = 0.f;
    #pragma unroll
    for (int d = 0; d < 16; ++d) {
        float wrv = wr[d * 256 + t];
        float wiv = wi[d * 256 + t];
        tr += wrv * cd[d] - wiv * sd[d];
        ti += wrv * sd[d] + wiv * cd[d];
    }
    Tr[t] = tr;
    Ti[t] = ti;
    __syncthreads();

    float acc = 0.f;
    for (int k = 0; k < 256; ++k) {
        int a = (k * t) & 255;
        acc += Tr[k] * cosT[a] + Ti[k] * sinT[a];
    }
    M[m * 256 + t] = acc * (1.0f / 64.0f);

    if (t == 0) {
        float s = 0.f;
        #pragma unroll
        for (int d = 0; d < 16; ++d) {
            float a = (2.0f * PI_F / 16.0f) * (float)((d * m) & 15);
            s += br[d] * cosf(a) - bi[d] * sinf(a);
        }
        v[m] = 0.25f * s;
    }
}

// ---------------------------------------------------------------------------
// prep2: A = conv_w @ M, u = conv_w @ v + conv_b; zero GN stats.
// ---------------------------------------------------------------------------
__global__ void prep2(const float* __restrict__ conv_w, const float* __restrict__ conv_b,
                      const float* __restrict__ M, const float* __restrict__ v,
                      float* __restrict__ A, float* __restrict__ u,
                      float* __restrict__ stats) {
    const int t = threadIdx.x;
    __shared__ float cw[256];
    __shared__ float Ms[16][256];
    cw[t] = conv_w[t];
    #pragma unroll
    for (int m = 0; m < 16; ++m) Ms[m][t] = M[m * 256 + t];
    __syncthreads();

    #pragma unroll
    for (int e = 0; e < 16; ++e) {
        float acc = 0.f;
        #pragma unroll
        for (int m = 0; m < 16; ++m) acc += cw[e * 16 + m] * Ms[m][t];
        A[e * 256 + t] = acc;
    }
    if (t < 16) {
        float acc = conv_b[t];
        #pragma unroll
        for (int m = 0; m < 16; ++m) acc += cw[t * 16 + m] * v[m];
        u[t] = acc;
    }
    if (t < 128) stats[t] = 0.f;
}

// ---------------------------------------------------------------------------
// main v2: K-split-4 x 4-patches-per-lane.
// grid 512 x 256 (block = 256 consecutive patches, 8 waves/CU).
// Wave: lane = (pg<<4) | j ; pg = k-quarter (rows 4pg..4pg+3), j = patch quad.
// Thread: 4 adjacent patches (Pbase..Pbase+3) x 16 e x 64 k. A-reads: 256 b128
// per thread (4x fewer than v1). Butterfly shfl_xor(16),(32) combines quarters.
// A stored in LDS with row stride 20 floats so the 4 distinct per-instr
// addresses hit 2-way-or-less bank groups (free).
// ---------------------------------------------------------------------------
__global__ __launch_bounds__(256, 2) void main_k(const float* __restrict__ x,
                                                 const float* __restrict__ ws,
                                                 float* __restrict__ out,
                                                 float* __restrict__ stats) {
    __shared__ float As[16 * 320];   // [e][s1*20 + w], w<16, pad 4/row
    __shared__ float Us[16];
    __shared__ float s_sum[8], s_ssq[8];
    const int t = threadIdx.x;

    {   // stage A into padded layout: t -> (e = t>>4, s1 = t&15)
        const int e = t >> 4, s1 = t & 15;
        const float4* src = (const float4*)(ws + WS_A + e * 256 + s1 * 16);
        float* dst = As + e * 320 + s1 * 20;
        float4 v0 = src[0], v1 = src[1], v2 = src[2], v3 = src[3];
        *(float4*)(dst + 0)  = v0;
        *(float4*)(dst + 4)  = v1;
        *(float4*)(dst + 8)  = v2;
        *(float4*)(dst + 12) = v3;
    }
    if (t < 16) Us[t] = ws[WS_U + t];
    if (t < 8) { s_sum[t] = 0.f; s_ssq[t] = 0.f; }
    __syncthreads();

    const int wv   = t >> 6;       // wave 0..3
    const int lane = t & 63;
    const int j    = lane & 15;    // patch-quad index within wave
    const int pg   = lane >> 4;    // k-quarter 0..3

    const int Pbase = (blockIdx.x << 8) + (wv << 6) + (j << 2); // 4 patches
    const int b  = Pbase >> 14;
    const int pi = Pbase & 16383;
    const int ph = pi >> 7;
    const int pw = pi & 127;       // multiple of 4

    // my 4 rows of the 4 patches: global rows ph*16 + pg*4 + r
    const float* xb = x + ((size_t)b << 22)
                        + (size_t)(ph * 16 + pg * 4) * 2048
                        + (size_t)(pw * 16);

    float acc[4][16];
    #pragma unroll
    for (int p = 0; p < 4; ++p)
        #pragma unroll
        for (int e = 0; e < 16; ++e) acc[p][e] = 0.f;

    #pragma unroll
    for (int r = 0; r < 4; ++r) {
        const float4* rp = (const float4*)(xb + (size_t)r * 2048);
        float4 pr[16];
        #pragma unroll
        for (int i = 0; i < 16; ++i) pr[i] = rp[i];   // 4 patches x 16 floats

        const int s1 = (pg << 2) + r;
        const float* Arow = As + s1 * 20;
        #pragma unroll
        for (int e = 0; e < 16; ++e) {
            const float* Ae = Arow + e * 320;
            const float4 a0 = *(const float4*)(Ae + 0);
            const float4 a1 = *(const float4*)(Ae + 4);
            const float4 a2 = *(const float4*)(Ae + 8);
            const float4 a3 = *(const float4*)(Ae + 12);
            #pragma unroll
            for (int p = 0; p < 4; ++p) {
                const float4 q0 = pr[p * 4 + 0];
                const float4 q1 = pr[p * 4 + 1];
                const float4 q2 = pr[p * 4 + 2];
                const float4 q3 = pr[p * 4 + 3];
                acc[p][e] += a0.x * q0.x + a0.y * q0.y + a0.z * q0.z + a0.w * q0.w
                           + a1.x * q1.x + a1.y * q1.y + a1.z * q1.z + a1.w * q1.w
                           + a2.x * q2.x + a2.y * q2.y + a2.z * q2.z + a2.w * q2.w
                           + a3.x * q3.x + a3.y * q3.y + a3.z * q3.z + a3.w * q3.w;
            }
        }
    }

    // combine k-quarters: butterfly over lane bits 4 and 5
    #pragma unroll
    for (int p = 0; p < 4; ++p)
        #pragma unroll
        for (int e = 0; e < 16; ++e)
            acc[p][e] += __shfl_xor(acc[p][e], 16, 64);
    #pragma unroll
    for (int p = 0; p < 4; ++p)
        #pragma unroll
        for (int e = 0; e < 16; ++e)
            acc[p][e] += __shfl_xor(acc[p][e], 32, 64);

    // each lane now owns patch Pbase+pg (64 distinct patches per wave)
    const size_t obase = ((size_t)b << 18) + (size_t)(ph << 7) + (size_t)(pw + pg);

    float sv[8], qv[8];
    #pragma unroll
    for (int g = 0; g < 8; ++g) {
        float v0 = acc[pg][2 * g]     + Us[2 * g];
        float v1 = acc[pg][2 * g + 1] + Us[2 * g + 1];
        out[obase + (size_t)(2 * g) * 16384]     = v0;
        out[obase + (size_t)(2 * g + 1) * 16384] = v1;
        sv[g] = v0 + v1;
        qv[g] = v0 * v0 + v1 * v1;
    }
    #pragma unroll
    for (int off = 32; off > 0; off >>= 1) {
        #pragma unroll
        for (int g = 0; g < 8; ++g) {
            sv[g] += __shfl_xor(sv[g], off, 64);
            qv[g] += __shfl_xor(qv[g], off, 64);
        }
    }
    if ((t & 63) == 0) {
        #pragma unroll
        for (int g = 0; g < 8; ++g) {
            atomicAdd(&s_sum[g], sv[g]);
            atomicAdd(&s_ssq[g], qv[g]);
        }
    }
    __syncthreads();
    if (t < 8) {
        atomicAdd(&stats[b * 8 + t],      s_sum[t]);
        atomicAdd(&stats[64 + b * 8 + t], s_ssq[t]);
    }
}

// ---------------------------------------------------------------------------
// finalize: in-place GroupNorm on d_out using accumulated stats.
// ---------------------------------------------------------------------------
__global__ __launch_bounds__(256) void finalize(float* __restrict__ out,
                                                const float* __restrict__ stats,
                                                const float* __restrict__ gamma,
                                                const float* __restrict__ beta) {
    const int i    = blockIdx.x * 256 + threadIdx.x;  // float4 index
    const int flat = i << 2;
    const int b = flat >> 18;
    const int c = (flat >> 14) & 15;
    const int g = c >> 1;

    const float inv_n = 1.0f / 32768.0f;
    float mean = stats[b * 8 + g] * inv_n;
    float var  = stats[64 + b * 8 + g] * inv_n - mean * mean;
    float rstd = rsqrtf(var + 1e-5f);
    float sc = rstd * gamma[c];
    float sh = beta[c] - mean * sc;

    float4 vv = ((float4*)out)[i];
    vv.x = vv.x * sc + sh;
    vv.y = vv.y * sc + sh;
    vv.z = vv.z * sc + sh;
    vv.w = vv.w * sc + sh;
    ((float4*)out)[i] = vv;
}

extern "C" void kernel_launch(void* const* d_in, const int* in_sizes, int n_in,
                              void* d_out, int out_size, void* d_ws, size_t ws_size,
                              hipStream_t stream) {
    const float* x  = (const float*)d_in[0];
    const float* wr = (const float*)d_in[1];
    const float* wi = (const float*)d_in[2];
    const float* br = (const float*)d_in[3];
    const float* bi = (const float*)d_in[4];
    const float* cw = (const float*)d_in[5];
    const float* cb = (const float*)d_in[6];
    const float* gm = (const float*)d_in[7];
    const float* bt = (const float*)d_in[8];
    float* out = (float*)d_out;
    float* ws  = (float*)d_ws;

    prep1<<<16, 256, 0, stream>>>(wr, wi, br, bi, ws + WS_M, ws + WS_V);
    prep2<<<1, 256, 0, stream>>>(cw, cb, ws + WS_M, ws + WS_V,
                                 ws + WS_A, ws + WS_U, ws + WS_STATS);
    main_k<<<512, 256, 0, stream>>>(x, ws, out, ws + WS_STATS);
    finalize<<<2048, 256, 0, stream>>>(out, ws + WS_STATS, gm, bt);
}

// Round 6
// 229.828 us; speedup vs baseline: 1.5689x; 1.5689x over previous
//
#include <hip/hip_runtime.h>
#include <math.h>

#define PI_F 3.14159265358979323846f

// Problem constants: x (8,1,2048,2048) fp32 -> out (8,16,128,128) fp32
// Patches: 16x16, D_in=256, D=16, 131072 patches total (16384 per batch).

// Workspace float offsets
#define WS_M     0      // M[16][256]
#define WS_V     4096   // v[16]
#define WS_A     4352   // A[16][256]
#define WS_U     8448   // u[16]
#define WS_STATS 8464   // sum[64], sumsq[64]

// ---------------------------------------------------------------------------
// prep1: M[m][n] = (1/64) Re( sum_k e^{-2pi i k n/256} * T[m][k] )
//        T[m][k] = sum_d Wc[d][k] e^{+2pi i d m/16},  Wc = wr + i*wi
//        v[m]    = (1/4)  Re( sum_d (br[d]+i*bi[d]) e^{+2pi i d m/16} )
// ---------------------------------------------------------------------------
__global__ void prep1(const float* __restrict__ wr, const float* __restrict__ wi,
                      const float* __restrict__ br, const float* __restrict__ bi,
                      float* __restrict__ M, float* __restrict__ v) {
    const int m = blockIdx.x;
    const int t = threadIdx.x;
    __shared__ float Tr[256], Ti[256], cosT[256], sinT[256], cd[16], sd[16];

    float ang = (2.0f * PI_F / 256.0f) * (float)t;
    cosT[t] = cosf(ang);
    sinT[t] = sinf(ang);
    if (t < 16) {
        float a = (2.0f * PI_F / 16.0f) * (float)((t * m) & 15);
        cd[t] = cosf(a);
        sd[t] = sinf(a);
    }
    __syncthreads();

    float tr = 0.f, ti = 0.f;
    #pragma unroll
    for (int d = 0; d < 16; ++d) {
        float wrv = wr[d * 256 + t];
        float wiv = wi[d * 256 + t];
        tr += wrv * cd[d] - wiv * sd[d];
        ti += wrv * sd[d] + wiv * cd[d];
    }
    Tr[t] = tr;
    Ti[t] = ti;
    __syncthreads();

    float acc = 0.f;
    for (int k = 0; k < 256; ++k) {
        int a = (k * t) & 255;
        acc += Tr[k] * cosT[a] + Ti[k] * sinT[a];
    }
    M[m * 256 + t] = acc * (1.0f / 64.0f);

    if (t == 0) {
        float s = 0.f;
        #pragma unroll
        for (int d = 0; d < 16; ++d) {
            float a = (2.0f * PI_F / 16.0f) * (float)((d * m) & 15);
            s += br[d] * cosf(a) - bi[d] * sinf(a);
        }
        v[m] = 0.25f * s;
    }
}

// ---------------------------------------------------------------------------
// prep2: A = conv_w @ M, u = conv_w @ v + conv_b; zero GN stats.
// ---------------------------------------------------------------------------
__global__ void prep2(const float* __restrict__ conv_w, const float* __restrict__ conv_b,
                      const float* __restrict__ M, const float* __restrict__ v,
                      float* __restrict__ A, float* __restrict__ u,
                      float* __restrict__ stats) {
    const int t = threadIdx.x;
    __shared__ float cw[256];
    __shared__ float Ms[16][256];
    cw[t] = conv_w[t];
    #pragma unroll
    for (int m = 0; m < 16; ++m) Ms[m][t] = M[m * 256 + t];
    __syncthreads();

    #pragma unroll
    for (int e = 0; e < 16; ++e) {
        float acc = 0.f;
        #pragma unroll
        for (int m = 0; m < 16; ++m) acc += cw[e * 16 + m] * Ms[m][t];
        A[e * 256 + t] = acc;
    }
    if (t < 16) {
        float acc = conv_b[t];
        #pragma unroll
        for (int m = 0; m < 16; ++m) acc += cw[t * 16 + m] * v[m];
        u[t] = acc;
    }
    if (t < 128) stats[t] = 0.f;
}

// ---------------------------------------------------------------------------
// main v4: R1 structure + 2 adjacent patches per thread.
// A staged in LDS [16][256]; all A-reads are wave-uniform broadcast
// ds_read_b128 (0 conflicts, issue-cost only) and each is reused for 2
// patches -> half the waves of R1 => LDS-pipe time ~20 us ~= HBM floor.
// Live regs ~95 (acc 32 + rows 32 + frag 16 + addr) -> no spills.
// grid 256 x 256 (block = 512 consecutive patches).
// ---------------------------------------------------------------------------
__global__ __launch_bounds__(256) void main_k(const float* __restrict__ x,
                                              const float* __restrict__ ws,
                                              float* __restrict__ out,
                                              float* __restrict__ stats) {
    __shared__ float As[4096];
    __shared__ float Us[16];
    __shared__ float s_sum[8], s_ssq[8];
    const int t = threadIdx.x;

    const float4* Ag  = (const float4*)(ws + WS_A);
    float4*       As4 = (float4*)As;
    #pragma unroll
    for (int i = 0; i < 4; ++i) As4[t + 256 * i] = Ag[t + 256 * i];
    if (t < 16) Us[t] = ws[WS_U + t];
    if (t < 8) { s_sum[t] = 0.f; s_ssq[t] = 0.f; }
    __syncthreads();

    const int P0 = (blockIdx.x << 9) + (t << 1);  // first of 2 adjacent patches
    const int b  = P0 >> 14;
    const int pi = P0 & 16383;
    const int ph = pi >> 7;
    const int pw = pi & 127;                       // even

    const float* xb = x + ((size_t)b << 22) + (size_t)(ph << 4) * 2048 + ((size_t)pw << 4);

    float acc0[16], acc1[16];
    #pragma unroll
    for (int e = 0; e < 16; ++e) { acc0[e] = 0.f; acc1[e] = 0.f; }

    #pragma unroll 1
    for (int s1 = 0; s1 < 16; ++s1) {
        const float4* rp = (const float4*)(xb + (size_t)s1 * 2048);
        float4 p0 = rp[0], p1 = rp[1], p2 = rp[2], p3 = rp[3];   // patch0 row
        float4 q0 = rp[4], q1 = rp[5], q2 = rp[6], q3 = rp[7];   // patch1 row

        const float* Arow = As + s1 * 16;
        #pragma unroll
        for (int e = 0; e < 16; ++e) {
            const float* Ae = Arow + (e << 8);
            const float4 a0 = *(const float4*)(Ae + 0);
            const float4 a1 = *(const float4*)(Ae + 4);
            const float4 a2 = *(const float4*)(Ae + 8);
            const float4 a3 = *(const float4*)(Ae + 12);
            acc0[e] += a0.x * p0.x + a0.y * p0.y + a0.z * p0.z + a0.w * p0.w
                     + a1.x * p1.x + a1.y * p1.y + a1.z * p1.z + a1.w * p1.w
                     + a2.x * p2.x + a2.y * p2.y + a2.z * p2.z + a2.w * p2.w
                     + a3.x * p3.x + a3.y * p3.y + a3.z * p3.z + a3.w * p3.w;
            acc1[e] += a0.x * q0.x + a0.y * q0.y + a0.z * q0.z + a0.w * q0.w
                     + a1.x * q1.x + a1.y * q1.y + a1.z * q1.z + a1.w * q1.w
                     + a2.x * q2.x + a2.y * q2.y + a2.z * q2.z + a2.w * q2.w
                     + a3.x * q3.x + a3.y * q3.y + a3.z * q3.z + a3.w * q3.w;
        }
    }

    // bias + coalesced float2 stores + per-group stats
    float sv[8], qv[8];
    const size_t obase = ((size_t)b << 18) + (size_t)(ph << 7) + (size_t)pw;
    #pragma unroll
    for (int g = 0; g < 8; ++g) {
        const int c0 = 2 * g, c1 = 2 * g + 1;
        float u0 = Us[c0], u1 = Us[c1];
        float va = acc0[c0] + u0, vb = acc1[c0] + u0;   // channel c0, patches 0/1
        float vc = acc0[c1] + u1, vd = acc1[c1] + u1;   // channel c1, patches 0/1
        *(float2*)&out[obase + (size_t)c0 * 16384] = make_float2(va, vb);
        *(float2*)&out[obase + (size_t)c1 * 16384] = make_float2(vc, vd);
        sv[g] = va + vb + vc + vd;
        qv[g] = va * va + vb * vb + vc * vc + vd * vd;
    }
    #pragma unroll
    for (int off = 32; off > 0; off >>= 1) {
        #pragma unroll
        for (int g = 0; g < 8; ++g) {
            sv[g] += __shfl_xor(sv[g], off, 64);
            qv[g] += __shfl_xor(qv[g], off, 64);
        }
    }
    if ((t & 63) == 0) {
        #pragma unroll
        for (int g = 0; g < 8; ++g) {
            atomicAdd(&s_sum[g], sv[g]);
            atomicAdd(&s_ssq[g], qv[g]);
        }
    }
    __syncthreads();
    if (t < 8) {
        atomicAdd(&stats[b * 8 + t],      s_sum[t]);
        atomicAdd(&stats[64 + b * 8 + t], s_ssq[t]);
    }
}

// ---------------------------------------------------------------------------
// finalize: in-place GroupNorm on d_out using accumulated stats.
// ---------------------------------------------------------------------------
__global__ __launch_bounds__(256) void finalize(float* __restrict__ out,
                                                const float* __restrict__ stats,
                                                const float* __restrict__ gamma,
                                                const float* __restrict__ beta) {
    const int i    = blockIdx.x * 256 + threadIdx.x;  // float4 index
    const int flat = i << 2;
    const int b = flat >> 18;
    const int c = (flat >> 14) & 15;
    const int g = c >> 1;

    const float inv_n = 1.0f / 32768.0f;
    float mean = stats[b * 8 + g] * inv_n;
    float var  = stats[64 + b * 8 + g] * inv_n - mean * mean;
    float rstd = rsqrtf(var + 1e-5f);
    float sc = rstd * gamma[c];
    float sh = beta[c] - mean * sc;

    float4 vv = ((float4*)out)[i];
    vv.x = vv.x * sc + sh;
    vv.y = vv.y * sc + sh;
    vv.z = vv.z * sc + sh;
    vv.w = vv.w * sc + sh;
    ((float4*)out)[i] = vv;
}

extern "C" void kernel_launch(void* const* d_in, const int* in_sizes, int n_in,
                              void* d_out, int out_size, void* d_ws, size_t ws_size,
                              hipStream_t stream) {
    const float* x  = (const float*)d_in[0];
    const float* wr = (const float*)d_in[1];
    const float* wi = (const float*)d_in[2];
    const float* br = (const float*)d_in[3];
    const float* bi = (const float*)d_in[4];
    const float* cw = (const float*)d_in[5];
    const float* cb = (const float*)d_in[6];
    const float* gm = (const float*)d_in[7];
    const float* bt = (const float*)d_in[8];
    float* out = (float*)d_out;
    float* ws  = (float*)d_ws;

    prep1<<<16, 256, 0, stream>>>(wr, wi, br, bi, ws + WS_M, ws + WS_V);
    prep2<<<1, 256, 0, stream>>>(cw, cb, ws + WS_M, ws + WS_V,
                                 ws + WS_A, ws + WS_U, ws + WS_STATS);
    main_k<<<256, 256, 0, stream>>>(x, ws, out, ws + WS_STATS);
    finalize<<<2048, 256, 0, stream>>>(out, ws + WS_STATS, gm, bt);
}

// Round 7
// 224.337 us; speedup vs baseline: 1.6073x; 1.0245x over previous
//
#include <hip/hip_runtime.h>
#include <math.h>

#define PI_F 3.14159265358979323846f

// Problem constants: x (8,1,2048,2048) fp32 -> out (8,16,128,128) fp32
// Patches: 16x16, D_in=256, D=16, 131072 patches total (16384 per batch).

// Workspace float offsets
#define WS_M     0      // M[16][256] fp32
#define WS_V     4096   // v[16]
#define WS_A     4352   // A[16][256] fp32
#define WS_U     8448   // u[16]
#define WS_STATS 8464   // sum[64], sumsq[64]
#define WS_AH    8592   // A as fp16 [16][256] (2048 dwords)

using half8  = __attribute__((ext_vector_type(8))) _Float16;
using floatx4 = __attribute__((ext_vector_type(4))) float;

// ---------------------------------------------------------------------------
// prep1: M[m][n] = (1/64) Re( sum_k e^{-2pi i k n/256} * T[m][k] )
// ---------------------------------------------------------------------------
__global__ void prep1(const float* __restrict__ wr, const float* __restrict__ wi,
                      const float* __restrict__ br, const float* __restrict__ bi,
                      float* __restrict__ M, float* __restrict__ v) {
    const int m = blockIdx.x;
    const int t = threadIdx.x;
    __shared__ float Tr[256], Ti[256], cosT[256], sinT[256], cd[16], sd[16];

    float ang = (2.0f * PI_F / 256.0f) * (float)t;
    cosT[t] = cosf(ang);
    sinT[t] = sinf(ang);
    if (t < 16) {
        float a = (2.0f * PI_F / 16.0f) * (float)((t * m) & 15);
        cd[t] = cosf(a);
        sd[t] = sinf(a);
    }
    __syncthreads();

    float tr = 0.f, ti = 0.f;
    #pragma unroll
    for (int d = 0; d < 16; ++d) {
        float wrv = wr[d * 256 + t];
        float wiv = wi[d * 256 + t];
        tr += wrv * cd[d] - wiv * sd[d];
        ti += wrv * sd[d] + wiv * cd[d];
    }
    Tr[t] = tr;
    Ti[t] = ti;
    __syncthreads();

    float acc = 0.f;
    for (int k = 0; k < 256; ++k) {
        int a = (k * t) & 255;
        acc += Tr[k] * cosT[a] + Ti[k] * sinT[a];
    }
    M[m * 256 + t] = acc * (1.0f / 64.0f);

    if (t == 0) {
        float s = 0.f;
        #pragma unroll
        for (int d = 0; d < 16; ++d) {
            float a = (2.0f * PI_F / 16.0f) * (float)((d * m) & 15);
            s += br[d] * cosf(a) - bi[d] * sinf(a);
        }
        v[m] = 0.25f * s;
    }
}

// ---------------------------------------------------------------------------
// prep2: A = conv_w @ M (fp32 + fp16 copy), u = conv_w @ v + conv_b; zero stats.
// ---------------------------------------------------------------------------
__global__ void prep2(const float* __restrict__ conv_w, const float* __restrict__ conv_b,
                      const float* __restrict__ M, const float* __restrict__ v,
                      float* __restrict__ ws) {
    const int t = threadIdx.x;
    float* A = ws + WS_A;
    _Float16* Ah = (_Float16*)(ws + WS_AH);
    __shared__ float cw[256];
    __shared__ float Ms[16][256];
    cw[t] = conv_w[t];
    #pragma unroll
    for (int m = 0; m < 16; ++m) Ms[m][t] = M[m * 256 + t];
    __syncthreads();

    #pragma unroll
    for (int e = 0; e < 16; ++e) {
        float acc = 0.f;
        #pragma unroll
        for (int m = 0; m < 16; ++m) acc += cw[e * 16 + m] * Ms[m][t];
        A[e * 256 + t] = acc;
        Ah[e * 256 + t] = (_Float16)acc;
    }
    if (t < 16) {
        float acc = conv_b[t];
        #pragma unroll
        for (int m = 0; m < 16; ++m) acc += cw[t * 16 + m] * v[m];
        ws[WS_U + t] = acc;
    }
    if (t < 128) ws[WS_STATS + t] = 0.f;
}

// ---------------------------------------------------------------------------
// main v5: MFMA GEMM. Block = 256 thr = 4 waves = 64 consecutive patches
// (one tile of 16 per wave). A-operand (patch data) loaded DIRECTLY from
// global into fragments (16 independent dwordx4/thread, fully unrolled ->
// deep pipelining, no per-iter vmcnt(0)). B-operand (A_mat fp16) staged in
// LDS, padded stride 264 (2-way max). C via LDS transpose -> coalesced
// float4 stores + GN stats. grid 2048 x 256.
// ---------------------------------------------------------------------------
__global__ __launch_bounds__(256) void main_k(const float* __restrict__ x,
                                              const float* __restrict__ ws,
                                              float* __restrict__ out,
                                              float* __restrict__ stats) {
    __shared__ _Float16 A_sh[16 * 264];   // [n][k], stride 264
    __shared__ float out_s[64 * 17];      // [p_local][ch], stride 17
    __shared__ float Us[16];
    __shared__ float s_sum[8], s_ssq[8];
    const int t = threadIdx.x;

    {   // stage A fp16 into padded LDS: thread t -> e=t>>4, n0=(t&15)*16
        const uint4* asrc = (const uint4*)(ws + WS_AH);
        uint4 q0 = asrc[t * 2];
        uint4 q1 = asrc[t * 2 + 1];
        _Float16* dp = A_sh + (t >> 4) * 264 + (t & 15) * 16;
        *(uint4*)dp       = q0;
        *(uint4*)(dp + 8) = q1;
    }
    if (t < 16) Us[t] = ws[WS_U + t];
    if (t < 8) { s_sum[t] = 0.f; s_ssq[t] = 0.f; }
    __syncthreads();

    const int w    = t >> 6;       // wave -> tile 0..3
    const int lane = t & 63;
    const int m    = lane & 15;    // patch-in-tile / channel index
    const int kg   = lane >> 4;    // k-group 0..3

    const int P0  = blockIdx.x << 6;   // 64 patches, same b, same ph
    const int b   = P0 >> 14;
    const int pi  = P0 & 16383;
    const int ph  = pi >> 7;
    const int pw0 = pi & 127;          // 0 or 64

    // this lane's patch top-left, plus its (kg) sub-row offset
    const float* xb = x + ((size_t)b << 22)
                        + (size_t)(ph << 4) * 2048
                        + (size_t)((pw0 + w * 16 + m) << 4);

    floatx4 acc = {0.f, 0.f, 0.f, 0.f};
    const int r_off = (kg >> 1);        // extra row within step
    const int c_off = (kg & 1) << 3;    // 0 or 8 floats

    #pragma unroll
    for (int s = 0; s < 8; ++s) {
        const float* px = xb + (size_t)(2 * s + r_off) * 2048 + c_off;
        float4 x0 = *(const float4*)px;
        float4 x1 = *(const float4*)(px + 4);
        half8 a;
        a[0] = (_Float16)x0.x; a[1] = (_Float16)x0.y;
        a[2] = (_Float16)x0.z; a[3] = (_Float16)x0.w;
        a[4] = (_Float16)x1.x; a[5] = (_Float16)x1.y;
        a[6] = (_Float16)x1.z; a[7] = (_Float16)x1.w;
        half8 bf = *(const half8*)&A_sh[m * 264 + s * 32 + kg * 8];
        acc = __builtin_amdgcn_mfma_f32_16x16x32_f16(a, bf, acc, 0, 0, 0);
    }

    // C layout: col(ch)=lane&15=m, row(patch)=(lane>>4)*4+reg
    #pragma unroll
    for (int r = 0; r < 4; ++r)
        out_s[(w * 16 + kg * 4 + r) * 17 + m] = acc[r];
    __syncthreads();

    // coalesced stores + bias + GN stats: thread t -> ch=t>>4, 4 patches
    const int ch = t >> 4;
    const int i4 = t & 15;
    const float u = Us[ch];
    float v0 = out_s[(i4 * 4 + 0) * 17 + ch] + u;
    float v1 = out_s[(i4 * 4 + 1) * 17 + ch] + u;
    float v2 = out_s[(i4 * 4 + 2) * 17 + ch] + u;
    float v3 = out_s[(i4 * 4 + 3) * 17 + ch] + u;
    *(float4*)&out[((size_t)b << 18) + (size_t)ch * 16384
                   + (size_t)(ph << 7) + (size_t)(pw0 + i4 * 4)]
        = make_float4(v0, v1, v2, v3);

    float sv = v0 + v1 + v2 + v3;
    float qv = v0 * v0 + v1 * v1 + v2 * v2 + v3 * v3;
    // lanes 0-31 of each wave share one group, 32-63 the other
    #pragma unroll
    for (int off = 1; off <= 16; off <<= 1) {
        sv += __shfl_xor(sv, off, 64);
        qv += __shfl_xor(qv, off, 64);
    }
    if ((lane & 31) == 0) {
        atomicAdd(&s_sum[ch >> 1], sv);
        atomicAdd(&s_ssq[ch >> 1], qv);
    }
    __syncthreads();
    if (t < 8) {
        atomicAdd(&stats[b * 8 + t],      s_sum[t]);
        atomicAdd(&stats[64 + b * 8 + t], s_ssq[t]);
    }
}

// ---------------------------------------------------------------------------
// finalize: in-place GroupNorm on d_out using accumulated stats.
// ---------------------------------------------------------------------------
__global__ __launch_bounds__(256) void finalize(float* __restrict__ out,
                                                const float* __restrict__ stats,
                                                const float* __restrict__ gamma,
                                                const float* __restrict__ beta) {
    const int i    = blockIdx.x * 256 + threadIdx.x;  // float4 index
    const int flat = i << 2;
    const int b = flat >> 18;
    const int c = (flat >> 14) & 15;
    const int g = c >> 1;

    const float inv_n = 1.0f / 32768.0f;
    float mean = stats[b * 8 + g] * inv_n;
    float var  = stats[64 + b * 8 + g] * inv_n - mean * mean;
    float rstd = rsqrtf(var + 1e-5f);
    float sc = rstd * gamma[c];
    float sh = beta[c] - mean * sc;

    float4 vv = ((float4*)out)[i];
    vv.x = vv.x * sc + sh;
    vv.y = vv.y * sc + sh;
    vv.z = vv.z * sc + sh;
    vv.w = vv.w * sc + sh;
    ((float4*)out)[i] = vv;
}

extern "C" void kernel_launch(void* const* d_in, const int* in_sizes, int n_in,
                              void* d_out, int out_size, void* d_ws, size_t ws_size,
                              hipStream_t stream) {
    const float* x  = (const float*)d_in[0];
    const float* wr = (const float*)d_in[1];
    const float* wi = (const float*)d_in[2];
    const float* br = (const float*)d_in[3];
    const float* bi = (const float*)d_in[4];
    const float* cw = (const float*)d_in[5];
    const float* cb = (const float*)d_in[6];
    const float* gm = (const float*)d_in[7];
    const float* bt = (const float*)d_in[8];
    float* out = (float*)d_out;
    float* ws  = (float*)d_ws;

    prep1<<<16, 256, 0, stream>>>(wr, wi, br, bi, ws + WS_M, ws + WS_V);
    prep2<<<1, 256, 0, stream>>>(cw, cb, ws + WS_M, ws + WS_V, ws);
    main_k<<<2048, 256, 0, stream>>>(x, ws, out, ws + WS_STATS);
    finalize<<<2048, 256, 0, stream>>>(out, ws + WS_STATS, gm, bt);
}